// Round 5
// baseline (189.013 us; speedup 1.0000x reference)
//
#include <hip/hip_runtime.h>

// --- MFMA fp16 LSTM, Round 16: 32x32x16 shape, packed b64 h-writes ---
// r12/r15 (95.6us, 29 phases): 512-thr blocks, 2/CU, 16x16x32 MFMA. Counters:
// VALUBusy 53%, MfmaUtil 23%, SQ_LDS_BANK_CONFLICT 4.36M (=587 cyc/CU-phase)
// from 8 scattered u16 h-writes per lane-phase (lane owns 4 gates of ONE unit
// per tile -> isolated u16 each). Overlap attempts (r13 group-alt, r15 sleep
// stagger) all null -> attack pipe WORK, not scheduling.
// r16: iso-FLOP switch to mfma_f32_32x32x16_f16. Same A bytes, same 10 b128
// reads/wave (h0 frags shared L0/L1), same gate math (verified 7-trans form),
// but lane owns 4 units x 4 gates (16 C-regs). A-row permutation
// row' = 8a + 4hi + g  <->  unit u_local = 4hi + a   (hi = lane>>5)
// makes a lane's 4 h-outputs CONSECUTIVE halfwords -> ONE ds_write_b64 per
// layer (8 u16 -> 2 b64). Block-permutation sig(col) = ((col&7)<<2)|(col>>3)
// on 16B blocks spreads write banks 4-way -> ~1-way; reads stay one linear
// b128/lane (sig folded into precomputed offsets; A/B k-maps consistent).
// Phase p: layer1(t=p) reads h0(p),h1(p-1); layer0(t=p+1) reads x(p+1),h0(p);
// 29 barriers. Weights pre-scaled (i/f/o by -log2e, g by +2log2e) -> bare exp2.

typedef _Float16 half8  __attribute__((ext_vector_type(8)));
typedef _Float16 half4v __attribute__((ext_vector_type(4)));
typedef float floatx4 __attribute__((ext_vector_type(4)));
typedef float f32x16  __attribute__((ext_vector_type(16)));

#define NFRAG 112
#define WS_BIAS_OFF (NFRAG * 1024)
#define K2 2.8853900817779268f      // 2*log2(e)

#if __has_builtin(__builtin_amdgcn_exp2f)
#define EXP2(v) __builtin_amdgcn_exp2f(v)
#else
#define EXP2(v) __expf(0.6931471805599453f * (v))
#endif
#define RCP(v) __builtin_amdgcn_rcpf(v)
#define SIG(c) ((((c) & 7) << 2) | ((c) >> 3))

__global__ void prep_kernel(const float* __restrict__ Wih0, const float* __restrict__ Whh0,
                            const float* __restrict__ bih0, const float* __restrict__ bhh0,
                            const float* __restrict__ Wih1, const float* __restrict__ Whh1,
                            const float* __restrict__ bih1, const float* __restrict__ bhh1,
                            _Float16* __restrict__ wA, float* __restrict__ wBias) {
    int idx = blockIdx.x * blockDim.x + threadIdx.x;
    if (idx < NFRAG * 512) {
        int f = idx >> 9, slot = idx & 511;
        int lane = slot >> 3, j = slot & 7;
        int w, kt, layer;
        if (f < 48) { layer = 0; w = f / 6; kt = f % 6; }
        else        { layer = 1; int f2 = f - 48; w = f2 >> 3; kt = f2 & 7; }
        // architectural C-row r within the wave's 32 rows -> (unit, gate):
        int r  = lane & 31;
        int a  = r >> 3, hi = (r >> 2) & 1, g = r & 3;
        int u  = w * 8 + 4 * hi + a;
        int wrow = g * 64 + u;
        int k = kt * 16 + (lane >> 5) * 8 + j;
        float v;
        if (layer == 0) {
            if (k < 28)       v = Wih0[wrow * 28 + k];
            else if (k == 28) v = bih0[wrow] + bhh0[wrow];
            else if (k < 32)  v = 0.f;
            else              v = Whh0[wrow * 64 + (k - 32)];
        } else {
            if (k < 64)       v = Wih1[wrow * 64 + k];
            else              v = Whh1[wrow * 64 + (k - 64)];
        }
        float s = (g == 2) ? K2 : -1.4426950408889634f;
        wA[idx] = (_Float16)(v * s);
    } else if (idx < NFRAG * 512 + 256) {
        int m = idx - NFRAG * 512;
        int g = m & 3;
        int row = g * 64 + (m >> 2);
        float s = (g == 2) ? K2 : -1.4426950408889634f;
        wBias[m] = (bih1[row] + bhh1[row]) * s;   // wBias[u*4+g]
    }
}

// Breadth-first gate batch on PRE-SCALED accs (r12-verified math).
// accs[i>>2] regs [4*(i&3) .. +3] = (i,f,g,o) preacts of one unit.
// cn = [c*pg*pi + (eg-1)*pf] / (pf*pg*pi)  (1 rcp); h = (ec-1)/(ec*po+po).
template <int N>
__device__ __forceinline__ void gateN(const f32x16* accs, float* c, half4v* hout) {
    float ei[N], ef[N], eg[N], eo[N];
    #pragma unroll
    for (int i = 0; i < N; ++i) {
        ei[i] = EXP2(accs[i >> 2][4 * (i & 3) + 0]);
        ef[i] = EXP2(accs[i >> 2][4 * (i & 3) + 1]);
        eg[i] = EXP2(accs[i >> 2][4 * (i & 3) + 2]);
        eo[i] = EXP2(accs[i >> 2][4 * (i & 3) + 3]);
    }
    float num[N], rd[N], po[N];
    #pragma unroll
    for (int i = 0; i < N; ++i) {
        float pi = 1.0f + ei[i];
        float pf = 1.0f + ef[i];
        float pg = 1.0f + eg[i];
        po[i] = 1.0f + eo[i];
        float m = pg * pi;
        num[i] = c[i] * m + (eg[i] - 1.0f) * pf;
        rd[i]  = RCP(pf * m);
    }
    float ec[N];
    #pragma unroll
    for (int i = 0; i < N; ++i) {
        float cn = num[i] * rd[i];
        c[i] = cn;
        ec[i] = EXP2(K2 * cn);
    }
    #pragma unroll
    for (int i = 0; i < N; ++i) {
        float r2 = RCP(ec[i] * po[i] + po[i]);
        hout[i >> 2][i & 3] = (_Float16)((ec[i] - 1.0f) * r2);
    }
}

__device__ __forceinline__ f32x16 zero16() {
    f32x16 z;
    #pragma unroll
    for (int i = 0; i < 16; ++i) z[i] = 0.f;
    return z;
}

__launch_bounds__(512, 4)
__global__ void lstm_mfma(const float* __restrict__ x,
                          const _Float16* __restrict__ wA,
                          const float* __restrict__ wBias,
                          const float* __restrict__ Wlin, const float* __restrict__ blin,
                          float* __restrict__ out) {
    __shared__ __align__(16) _Float16 h0p[2][2048];  // [parity][K64 x n32 frag-linear]
    __shared__ __align__(16) _Float16 h1p[2][2048];
    __shared__ __align__(16) _Float16 xb[2][1024];   // K32 x n32
    __shared__ float wlin_s[640];
    __shared__ float blin_s[10];

    const int lane = threadIdx.x;
    const int w    = threadIdx.y;      // 0..7, owns units 8w..8w+7
    const int tid  = w * 64 + lane;
    const int col  = lane & 31;
    const int hi   = lane >> 5;

    // ---- A fragments: L0 6 frags (K96), L1 8 frags (K128) ----
    half8 A0[6], A1[8];
    #pragma unroll
    for (int kt = 0; kt < 6; ++kt)
        A0[kt] = *(const half8*)(wA + (w * 6 + kt) * 512 + lane * 8);
    #pragma unroll
    for (int kt = 0; kt < 8; ++kt)
        A1[kt] = *(const half8*)(wA + (48 + w * 8 + kt) * 512 + lane * 8);

    // bias for L1: lane's 4 units = 4hi + a
    f32x16 bias1;
    #pragma unroll
    for (int a = 0; a < 4; ++a) {
        floatx4 b = *(const floatx4*)(wBias + (w * 8 + 4 * hi + a) * 4);
        bias1[4 * a + 0] = b[0]; bias1[4 * a + 1] = b[1];
        bias1[4 * a + 2] = b[2]; bias1[4 * a + 3] = b[3];
    }

    // t-invariant LDS offsets (halfwords)
    const int roff = ((lane >> 5) * 32 + SIG(lane & 31)) * 8;  // B-frag b128 read
    const int woff = w * 256 + SIG(col) * 8 + 4 * hi;          // packed b64 h-write

    // ---- x staging: thread covers (k=ks, cols cs and cs+16) ----
    const int ks = tid & 31;
    const int cs = tid >> 5;           // 0..15
    const bool xvalid = ks < 28;
    const float* xg = x + (blockIdx.x * 32 + cs) * 784 + ks;
    const int xstg0 = (ks >> 3) * 256 + SIG(cs) * 8 + (ks & 7);
    const int xstg1 = (ks >> 3) * 256 + SIG(cs + 16) * 8 + (ks & 7);

    // ---- init: zero h(-1) planes, stage x(0) ----
    {
        ((int*)&h0p[1][0])[tid * 2 + 0] = 0;
        ((int*)&h0p[1][0])[tid * 2 + 1] = 0;
        ((int*)&h1p[1][0])[tid * 2 + 0] = 0;
        ((int*)&h1p[1][0])[tid * 2 + 1] = 0;
        float xv0 = xvalid ? xg[0] : 0.f;
        float xv1 = xvalid ? xg[16 * 784] : 0.f;
        xb[0][xstg0] = (ks == 28) ? (_Float16)1.0f : (_Float16)xv0;
        xb[0][xstg1] = (ks == 28) ? (_Float16)1.0f : (_Float16)xv1;
    }
    __syncthreads();

    float c0[4] = {0.f, 0.f, 0.f, 0.f};
    float c1[4] = {0.f, 0.f, 0.f, 0.f};

    for (int p = -1; p <= 27; ++p) {
        const int pr  = p & 1;
        const int pr1 = pr ^ 1;
        const bool doL0 = (p < 27);
        const bool doL1 = (p >= 0);

        // (1) global prefetch x(p+2)
        float xn0 = 0.f, xn1 = 0.f;
        if (p <= 25 && xvalid) {
            xn0 = xg[(p + 2) * 28];
            xn1 = xg[16 * 784 + (p + 2) * 28];
        }

        // (2) up-front B-frag reads: bx (2) + bh0 (4)
        half8 bx[2], bh0[4];
        if (doL0) {
            bx[0] = *(const half8*)&xb[pr1][roff];
            bx[1] = *(const half8*)&xb[pr1][512 + roff];
        }
        #pragma unroll
        for (int kt = 0; kt < 4; ++kt)
            bh0[kt] = *(const half8*)&h0p[pr][kt * 512 + roff];

        // (3) L0 MFMAs + L1 h0-part MFMAs
        f32x16 acc0, acc1;
        if (doL0) {
            acc0 = __builtin_amdgcn_mfma_f32_32x32x16_f16(A0[0], bx[0], zero16(), 0, 0, 0);
            acc0 = __builtin_amdgcn_mfma_f32_32x32x16_f16(A0[1], bx[1], acc0, 0, 0, 0);
            #pragma unroll
            for (int kt = 0; kt < 4; ++kt)
                acc0 = __builtin_amdgcn_mfma_f32_32x32x16_f16(A0[2 + kt], bh0[kt], acc0, 0, 0, 0);
        }
        if (doL1) {
            acc1 = bias1;
            #pragma unroll
            for (int kt = 0; kt < 4; ++kt)
                acc1 = __builtin_amdgcn_mfma_f32_32x32x16_f16(A1[kt], bh0[kt], acc1, 0, 0, 0);

            // (4) bh1 reads then L1 tail MFMAs
            half8 bh1[4];
            #pragma unroll
            for (int kt = 0; kt < 4; ++kt)
                bh1[kt] = *(const half8*)&h1p[pr1][kt * 512 + roff];
            #pragma unroll
            for (int kt = 0; kt < 4; ++kt)
                acc1 = __builtin_amdgcn_mfma_f32_32x32x16_f16(A1[4 + kt], bh1[kt], acc1, 0, 0, 0);
        }

        // (5) gates -> packed b64 writes
        if (doL0 && doL1) {
            f32x16 accs[2] = {acc0, acc1};
            float cc[8] = {c0[0], c0[1], c0[2], c0[3], c1[0], c1[1], c1[2], c1[3]};
            half4v h[2];
            gateN<8>(accs, cc, h);
            c0[0] = cc[0]; c0[1] = cc[1]; c0[2] = cc[2]; c0[3] = cc[3];
            c1[0] = cc[4]; c1[1] = cc[5]; c1[2] = cc[6]; c1[3] = cc[7];
            *(half4v*)&h0p[pr1][woff] = h[0];
            *(half4v*)&h1p[pr][woff]  = h[1];
        } else if (doL0) {
            f32x16 accs[1] = {acc0};
            half4v h[1];
            gateN<4>(accs, c0, h);
            *(half4v*)&h0p[pr1][woff] = h[0];
        } else {
            f32x16 accs[1] = {acc1};
            half4v h[1];
            gateN<4>(accs, c1, h);
            *(half4v*)&h1p[pr][woff] = h[0];
        }

        // (6) x staging, then barrier
        if (p <= 25) {
            xb[pr][xstg0] = (ks == 28) ? (_Float16)1.0f : (_Float16)xn0;
            xb[pr][xstg1] = (ks == 28) ? (_Float16)1.0f : (_Float16)xn1;
        }
        __syncthreads();
    }

    // ---- epilogue: out = h1(27) @ Wlin^T + blin ----
    wlin_s[tid] = Wlin[tid];
    if (tid < 128) wlin_s[512 + tid] = Wlin[512 + tid];
    if (tid < 10)  blin_s[tid] = blin[tid];
    __syncthreads();
    if (tid < 320) {
        int b = tid / 10, o = tid - b * 10;
        int sb = SIG(b);
        float a = blin_s[o];
        #pragma unroll 8
        for (int uu = 0; uu < 64; ++uu) {
            float hv = (float)h1p[1][(uu >> 3) * 256 + sb * 8 + (uu & 7)];
            a += wlin_s[o * 64 + uu] * hv;
        }
        out[(blockIdx.x * 32 + b) * 10 + o] = a;
    }
}

extern "C" void kernel_launch(void* const* d_in, const int* in_sizes, int n_in,
                              void* d_out, int out_size, void* d_ws, size_t ws_size,
                              hipStream_t stream) {
    const float* x    = (const float*)d_in[0];
    const float* Wih0 = (const float*)d_in[1];
    const float* Whh0 = (const float*)d_in[2];
    const float* bih0 = (const float*)d_in[3];
    const float* bhh0 = (const float*)d_in[4];
    const float* Wih1 = (const float*)d_in[5];
    const float* Whh1 = (const float*)d_in[6];
    const float* bih1 = (const float*)d_in[7];
    const float* bhh1 = (const float*)d_in[8];
    const float* Wlin = (const float*)d_in[9];
    const float* blin = (const float*)d_in[10];
    float* out = (float*)d_out;

    _Float16* wA    = (_Float16*)d_ws;
    float*    wBias = (float*)((char*)d_ws + WS_BIAS_OFF);

    prep_kernel<<<225, 256, 0, stream>>>(Wih0, Whh0, bih0, bhh0,
                                         Wih1, Whh1, bih1, bhh1, wA, wBias);
    lstm_mfma<<<512, dim3(64, 8), 0, stream>>>(x, wA, wBias, Wlin, blin, out);
}

// Round 6
// 177.204 us; speedup vs baseline: 1.0666x; 1.0666x over previous
//
#include <hip/hip_runtime.h>

// --- MFMA fp16 LSTM, Round 17: 4-wave blocks, 4 m-tiles/wave, 256 VGPR budget ---
// r12/r15 (95.6us, 29 phases, 16x16x32): per-CU-phase budget: VALU+trans 4.2k
// (53% busy), LDS 1.9-2.5k (160 b128 reads: 16 waves x 10, full B-panel each),
// MFMA 0.6k, barrier 0.7k; phase ~= SUM (convoy). Scheduling fixes all null
// (r13 group-alt +10us, r15 sleep-stagger +0, r16 32x32 shape -15us: spilled
// at 128-reg budget + 14-deep MFMA chains + worse write conflicts. REVERTED).
// r17 mechanical change: B-read redundancy = waves per batch-tile. 4 waves x
// 4 m-tiles (was 8 x 2): per-CU reads 160 -> 80 b128. A-frags 28 half8 = 112
// VGPR fit the 256-reg budget of __launch_bounds__(256,2) (2 waves/SIMD,
// 2 blocks/CU = 8 waves/CU). Gates as 4x gate4 (2 layers x 2 n-halves,
// n-sequential MFMA sections) to cap peak pressure ~220 regs, no spill.
// All r12-verified mappings preserved: prep layout, frag-linear planes,
// hwr/xrd/hrd formulas, pre-scaled weights (i/f/o -log2e, g +2log2e),
// 7-trans gate math (2 rcp + 5 exp2 per h). 29 barriers.

typedef _Float16 half8 __attribute__((ext_vector_type(8)));
typedef float floatx4 __attribute__((ext_vector_type(4)));

#define NFRAG 112
#define WS_BIAS_OFF (NFRAG * 1024)
#define K2 2.8853900817779268f      // 2*log2(e)

#if __has_builtin(__builtin_amdgcn_exp2f)
#define EXP2(v) __builtin_amdgcn_exp2f(v)
#else
#define EXP2(v) __expf(0.6931471805599453f * (v))
#endif
#define RCP(v) __builtin_amdgcn_rcpf(v)

__global__ void prep_kernel(const float* __restrict__ Wih0, const float* __restrict__ Whh0,
                            const float* __restrict__ bih0, const float* __restrict__ bhh0,
                            const float* __restrict__ Wih1, const float* __restrict__ Whh1,
                            const float* __restrict__ bih1, const float* __restrict__ bhh1,
                            _Float16* __restrict__ wA, float* __restrict__ wBias) {
    int idx = blockIdx.x * blockDim.x + threadIdx.x;
    if (idx < NFRAG * 512) {
        int f = idx >> 9, slot = idx & 511;
        int lane = slot >> 3, j = slot & 7;
        int mt, kt, layer;
        if (f < 48) { layer = 0; mt = f / 3; kt = f % 3; }
        else        { layer = 1; int f2 = f - 48; mt = f2 >> 2; kt = f2 & 3; }
        int m = mt * 16 + (lane & 15);
        int k = kt * 32 + (lane >> 4) * 8 + j;
        int u = m >> 2, g = m & 3;
        int row = g * 64 + u;
        float v;
        if (layer == 0) {
            if (k < 28)       v = Wih0[row * 28 + k];
            else if (k == 28) v = bih0[row] + bhh0[row];
            else if (k < 32)  v = 0.f;
            else              v = Whh0[row * 64 + (k - 32)];
        } else {
            if (k < 64)       v = Wih1[row * 64 + k];
            else              v = Whh1[row * 64 + (k - 64)];
        }
        float s = (g == 2) ? K2 : -1.4426950408889634f;
        wA[idx] = (_Float16)(v * s);
    } else if (idx < NFRAG * 512 + 256) {
        int m = idx - NFRAG * 512;
        int g = m & 3;
        int row = g * 64 + (m >> 2);
        float s = (g == 2) ? K2 : -1.4426950408889634f;
        wBias[m] = (bih1[row] + bhh1[row]) * s;
    }
}

// 4-wide breadth-first gate batch on PRE-SCALED accs (r12-verified math),
// single destination plane. cn = [c*pg*pi + (eg-1)*pf] / (pf*pg*pi) (1 rcp);
// h = (ec-1)/(ec*po+po), ec = 2^{K2*cn} (1 rcp).
__device__ __forceinline__ void gate4(const floatx4* acc, float* c,
                                      _Float16* plane, const int* offs) {
    float ei[4], ef[4], eg[4], eo[4];
    #pragma unroll
    for (int i = 0; i < 4; ++i) {
        floatx4 a = acc[i];
        ei[i] = EXP2(a[0]);
        ef[i] = EXP2(a[1]);
        eg[i] = EXP2(a[2]);
        eo[i] = EXP2(a[3]);
    }
    float num[4], rd[4], po[4];
    #pragma unroll
    for (int i = 0; i < 4; ++i) {
        float pi = 1.0f + ei[i];
        float pf = 1.0f + ef[i];
        float pg = 1.0f + eg[i];
        po[i] = 1.0f + eo[i];
        float m = pg * pi;
        num[i] = c[i] * m + (eg[i] - 1.0f) * pf;
        rd[i]  = RCP(pf * m);
    }
    float ec[4];
    #pragma unroll
    for (int i = 0; i < 4; ++i) {
        float cn = num[i] * rd[i];
        c[i] = cn;
        ec[i] = EXP2(K2 * cn);
    }
    #pragma unroll
    for (int i = 0; i < 4; ++i) {
        float r2 = RCP(ec[i] * po[i] + po[i]);
        plane[offs[i]] = (_Float16)((ec[i] - 1.0f) * r2);
    }
}

__launch_bounds__(256, 2)
__global__ void lstm_mfma(const float* __restrict__ x,
                          const _Float16* __restrict__ wA,
                          const float* __restrict__ wBias,
                          const float* __restrict__ Wlin, const float* __restrict__ blin,
                          float* __restrict__ out) {
    __shared__ __align__(16) _Float16 h0p[2][2048];  // [parity][frag-linear]
    __shared__ __align__(16) _Float16 h1p[2][2048];
    __shared__ __align__(16) _Float16 xb[2][1024];
    __shared__ float wlin_s[640];
    __shared__ float blin_s[10];

    const int lane = threadIdx.x;
    const int w    = threadIdx.y;      // 0..3
    const int tid  = w * 64 + lane;
    const int quad = lane >> 4;
    const int col  = lane & 15;
    const int l8   = lane * 8;

    // ---- A fragments: wave owns m-tiles MT = 4w+j, units u = MT*4+quad ----
    half8 A0[4][3], A1[4][4];
    floatx4 bias1[4];
    int hwr0[4];
    #pragma unroll
    for (int j = 0; j < 4; ++j) {
        const int MT = 4 * w + j;
        #pragma unroll
        for (int kt = 0; kt < 3; ++kt)
            A0[j][kt] = *(const half8*)(wA + (MT * 3 + kt) * 512 + l8);
        #pragma unroll
        for (int kt = 0; kt < 4; ++kt)
            A1[j][kt] = *(const half8*)(wA + (48 + MT * 4 + kt) * 512 + l8);
        const int u = MT * 4 + quad;
        bias1[j] = *(const floatx4*)(wBias + u * 4);
        hwr0[j] = (u >> 5) * 512 + (((u >> 3) & 3) * 16 + col) * 8 + (u & 7);
    }

    // ---- x staging: ks = tid&31, cs = tid>>5 (0..7); batches cs+8s ----
    const int ks = tid & 31;
    const int cs = tid >> 5;
    const bool xvalid = ks < 28;
    const bool xone   = (ks == 28);
    const float* xg = x + (blockIdx.x * 32 + cs) * 784 + ks;
    const int xstg0 = ((ks >> 3) * 16 + cs) * 8 + (ks & 7);
    // xstg(s) = xstg0 + (s&1)*64 + (s>>1)*512

    // ---- init: zero parity-1 planes, stage x(0) ----
    {
        #pragma unroll
        for (int k = 0; k < 4; ++k) {
            ((int*)&h0p[1][0])[tid * 4 + k] = 0;
            ((int*)&h1p[1][0])[tid * 4 + k] = 0;
        }
        #pragma unroll
        for (int s = 0; s < 4; ++s) {
            float xv = xvalid ? xg[s * 8 * 784] : 0.f;
            xb[0][xstg0 + (s & 1) * 64 + (s >> 1) * 512] =
                xone ? (_Float16)1.0f : (_Float16)xv;
        }
    }
    __syncthreads();

    float c0[2][4] = {{0.f, 0.f, 0.f, 0.f}, {0.f, 0.f, 0.f, 0.f}};  // [in][j]
    float c1[2][4] = {{0.f, 0.f, 0.f, 0.f}, {0.f, 0.f, 0.f, 0.f}};

    for (int p = -1; p <= 27; ++p) {
        const int pr  = p & 1;
        const int pr1 = pr ^ 1;
        const bool doL0 = (p < 27);
        const bool doL1 = (p >= 0);

        // (1) global prefetch x(p+2), 4 batch cols
        float xn[4] = {0.f, 0.f, 0.f, 0.f};
        if (p <= 25 && xvalid) {
            const float* xgp = xg + (p + 2) * 28;
            #pragma unroll
            for (int s = 0; s < 4; ++s) xn[s] = xgp[s * 8 * 784];
        }

        // (2) n-sequential halves: reads -> MFMAs -> gates per half
        #pragma unroll
        for (int in = 0; in < 2; ++in) {
            const int hb = in * 1024;   // plane offset for this n-half

            half8 bh0[2];
            #pragma unroll
            for (int kt = 0; kt < 2; ++kt)
                bh0[kt] = *(const half8*)&h0p[pr][hb + kt * 512 + l8];

            int offs[4];
            #pragma unroll
            for (int j = 0; j < 4; ++j) offs[j] = hwr0[j] + hb;

            if (doL0) {
                half8 bx = *(const half8*)&xb[pr1][in * 512 + l8];
                floatx4 acc0[4];
                #pragma unroll
                for (int j = 0; j < 4; ++j) {
                    acc0[j] = __builtin_amdgcn_mfma_f32_16x16x32_f16(
                                  A0[j][0], bx, (floatx4){0.f, 0.f, 0.f, 0.f}, 0, 0, 0);
                    #pragma unroll
                    for (int kt = 0; kt < 2; ++kt)
                        acc0[j] = __builtin_amdgcn_mfma_f32_16x16x32_f16(
                                      A0[j][kt + 1], bh0[kt], acc0[j], 0, 0, 0);
                }
                if (doL1) {
                    // L1 MFMAs before L0 gates: frees bh0 dependency early
                    floatx4 acc1[4];
                    half8 bh1[2];
                    #pragma unroll
                    for (int kt = 0; kt < 2; ++kt)
                        bh1[kt] = *(const half8*)&h1p[pr1][hb + kt * 512 + l8];
                    #pragma unroll
                    for (int j = 0; j < 4; ++j) {
                        acc1[j] = bias1[j];
                        #pragma unroll
                        for (int kt = 0; kt < 2; ++kt)
                            acc1[j] = __builtin_amdgcn_mfma_f32_16x16x32_f16(
                                          A1[j][kt], bh0[kt], acc1[j], 0, 0, 0);
                        #pragma unroll
                        for (int kt = 0; kt < 2; ++kt)
                            acc1[j] = __builtin_amdgcn_mfma_f32_16x16x32_f16(
                                          A1[j][kt + 2], bh1[kt], acc1[j], 0, 0, 0);
                    }
                    gate4(acc0, c0[in], &h0p[pr1][0], offs);
                    gate4(acc1, c1[in], &h1p[pr][0], offs);
                } else {
                    gate4(acc0, c0[in], &h0p[pr1][0], offs);
                }
            } else {
                // p == 27: L1 only
                floatx4 acc1[4];
                half8 bh1[2];
                #pragma unroll
                for (int kt = 0; kt < 2; ++kt)
                    bh1[kt] = *(const half8*)&h1p[pr1][hb + kt * 512 + l8];
                #pragma unroll
                for (int j = 0; j < 4; ++j) {
                    acc1[j] = bias1[j];
                    #pragma unroll
                    for (int kt = 0; kt < 2; ++kt)
                        acc1[j] = __builtin_amdgcn_mfma_f32_16x16x32_f16(
                                      A1[j][kt], bh0[kt], acc1[j], 0, 0, 0);
                    #pragma unroll
                    for (int kt = 0; kt < 2; ++kt)
                        acc1[j] = __builtin_amdgcn_mfma_f32_16x16x32_f16(
                                      A1[j][kt + 2], bh1[kt], acc1[j], 0, 0, 0);
                }
                gate4(acc1, c1[in], &h1p[pr][0], offs);
            }
        }

        // (3) x staging, then barrier
        if (p <= 25) {
            #pragma unroll
            for (int s = 0; s < 4; ++s)
                xb[pr][xstg0 + (s & 1) * 64 + (s >> 1) * 512] =
                    xone ? (_Float16)1.0f : (_Float16)xn[s];
        }
        __syncthreads();
    }

    // ---- epilogue: out = h1(27) @ Wlin^T + blin ----
    wlin_s[tid]       = Wlin[tid];
    wlin_s[tid + 256] = Wlin[tid + 256];
    if (tid < 128) wlin_s[tid + 512] = Wlin[tid + 512];
    if (tid < 10)  blin_s[tid] = blin[tid];
    __syncthreads();
    for (int e = tid; e < 320; e += 256) {
        int b = e / 10, o = e - b * 10;
        float a = blin_s[o];
        #pragma unroll 8
        for (int uu = 0; uu < 64; ++uu) {
            float hv = (float)h1p[1][((b >> 4) * 2 + (uu >> 5)) * 512 + (((uu >> 3) & 3) * 16 + (b & 15)) * 8 + (uu & 7)];
            a += wlin_s[o * 64 + uu] * hv;
        }
        out[(blockIdx.x * 32 + b) * 10 + o] = a;
    }
}

extern "C" void kernel_launch(void* const* d_in, const int* in_sizes, int n_in,
                              void* d_out, int out_size, void* d_ws, size_t ws_size,
                              hipStream_t stream) {
    const float* x    = (const float*)d_in[0];
    const float* Wih0 = (const float*)d_in[1];
    const float* Whh0 = (const float*)d_in[2];
    const float* bih0 = (const float*)d_in[3];
    const float* bhh0 = (const float*)d_in[4];
    const float* Wih1 = (const float*)d_in[5];
    const float* Whh1 = (const float*)d_in[6];
    const float* bih1 = (const float*)d_in[7];
    const float* bhh1 = (const float*)d_in[8];
    const float* Wlin = (const float*)d_in[9];
    const float* blin = (const float*)d_in[10];
    float* out = (float*)d_out;

    _Float16* wA    = (_Float16*)d_ws;
    float*    wBias = (float*)((char*)d_ws + WS_BIAS_OFF);

    prep_kernel<<<225, 256, 0, stream>>>(Wih0, Whh0, bih0, bhh0,
                                         Wih1, Whh1, bih1, bhh1, wA, wBias);
    lstm_mfma<<<512, dim3(64, 4), 0, stream>>>(x, wA, wBias, Wlin, blin, out);
}